// Round 5
// baseline (4526.991 us; speedup 1.0000x reference)
//
#include <hip/hip_runtime.h>
#include <stdint.h>

// R5: M=64 rows/block, 128 blocks, spill-proof rebuild of R4.
// - R4 post-mortem: `#pragma unroll 1` on jt + c_reg[jt] = dynamic reg-array
//   index -> c_reg demoted to scratch -> ~1 GB/kernel scratch traffic
//   (WRITE_SIZE 546 MB vs 25 MB legit). RULE: fully unroll every loop that
//   indexes a register array.
// - 16x16x32 MFMA, 4 fully-unrolled jt passes (N=128 cols each): peak live
//   ~190 regs < 256 cap at __launch_bounds__(512,2) (1 block/CU; LDS-bound
//   anyway). acc live = 64 (one jt), c_reg = 64 persistent.
// - K=544: x (4) + bias (1) + zero-pad folded into MFMA (R2-proven).
// - LDS: 2 x (64 x 552) bf16 double buffer = 141,312 B. LROW=552 -> 16B-aligned
//   rows, ~2-way bank aliasing on A-reads (free).
// - Per-XCD weight stream: 16 blocks x 2.2 MB = 35 MB/step (~8 us L2 floor),
//   half of R2. No cross-workgroup sync (R3 lesson).

#define LROW 552
#define BUF_SH (64 * LROW)        // 35328 shorts = 70656 B per buffer
#define KT_N 17                   // K tiles of 32 (544/32)
#define WMAT 1114112              // shorts per packed matrix: 32*17*4*512
#define B_TOT 4096

typedef __attribute__((ext_vector_type(8))) short short8;
typedef __attribute__((ext_vector_type(4))) float floatx4;

__device__ __forceinline__ unsigned short f2bf(float x) {
  union { float f; unsigned int u; } v; v.f = x;
  unsigned int u = v.u;
  return (unsigned short)((u + 0x7FFFu + ((u >> 16) & 1u)) >> 16);
}
__device__ __forceinline__ float bf2f(unsigned short s) {
  union { unsigned int u; float f; } v; v.u = ((unsigned int)s) << 16;
  return v.f;
}
__device__ __forceinline__ float rcpf(float x) { return __builtin_amdgcn_rcpf(x); }
__device__ __forceinline__ float sigm(float x) { return rcpf(1.0f + __expf(-x)); }
__device__ __forceinline__ float tanh_f(float x) {
  return 1.0f - 2.0f * rcpf(1.0f + __expf(2.0f * x));
}

// ---------------- prep: pack W_aug (bf16, 16x16x32 MFMA-B layout) ------------
// W_aug[n][ka]: ka<512 Wh; 512..515 Wi; 516 b; else 0.
// dst = mat*WMAT + ((nt*17 + kt)*4 + g)*512 + lane*8 + j
//   g = n>>9, c = n&511, nt = c>>4, ni = c&15
//   kt = ka>>5, quad = (ka>>3)&3, j = ka&7, lane = quad*16 + ni
__global__ void prep_weights(
    const float* __restrict__ Wh_s, const float* __restrict__ Wi_s, const float* __restrict__ b_s,
    const float* __restrict__ Wh_p, const float* __restrict__ Wi_p, const float* __restrict__ b_p,
    const float* __restrict__ Wh_d, const float* __restrict__ Wi_d, const float* __restrict__ b_d,
    const float* __restrict__ Wh_i, const float* __restrict__ Wi_i, const float* __restrict__ b_i,
    short* __restrict__ wpack)
{
  int idx = blockIdx.x * 256 + threadIdx.x;
  const int per = 2048 * 544;
  if (idx >= 4 * per) return;
  int mat = idx / per;
  int rem = idx - mat * per;
  int n = rem / 544;
  int ka = rem - n * 544;
  const float* Wh; const float* Wi; const float* bb;
  if (mat == 0)      { Wh = Wh_s; Wi = Wi_s; bb = b_s; }
  else if (mat == 1) { Wh = Wh_p; Wi = Wi_p; bb = b_p; }
  else if (mat == 2) { Wh = Wh_d; Wi = Wi_d; bb = b_d; }
  else               { Wh = Wh_i; Wi = Wi_i; bb = b_i; }
  float v;
  if (ka < 512)       v = Wh[n * 512 + ka];
  else if (ka < 516)  v = Wi[n * 4 + (ka - 512)];
  else if (ka == 516) v = bb[n];
  else                v = 0.0f;
  int g = n >> 9, c = n & 511, nt = c >> 4, ni = c & 15;
  int kt = ka >> 5, quad = (ka >> 3) & 3, j = ka & 7;
  int lane = quad * 16 + ni;
  wpack[(size_t)mat * WMAT + ((((size_t)nt * KT_N + kt) * 4 + g) << 9) + (lane << 3) + j] =
      (short)f2bf(v);
}

// ---------------- one LSTM step: all jt/mt/r/g loops FULLY unrolled ----------
__device__ __forceinline__ void lstm_step(
    const short* cur, short* nxt, const short* __restrict__ wm,
    int lane, int wv, float (&c_reg)[4][4][4])
{
  int m16 = lane & 15, quad = lane >> 4;
  const short* ap = cur + m16 * LROW + (quad << 3);
  #pragma unroll
  for (int jt = 0; jt < 4; ++jt) {
    int nt = jt * 8 + wv;
    const short* bp = wm + nt * (KT_N * 2048) + (lane << 3);
    floatx4 acc[4][4];
    #pragma unroll
    for (int mt = 0; mt < 4; ++mt)
      #pragma unroll
      for (int g = 0; g < 4; ++g) acc[mt][g] = (floatx4)0.0f;
    for (int kt = 0; kt < KT_N; ++kt) {
      short8 b0 = *(const short8*)(bp);
      short8 b1 = *(const short8*)(bp + 512);
      short8 b2 = *(const short8*)(bp + 1024);
      short8 b3 = *(const short8*)(bp + 1536);
      bp += 2048;
      const short* apk = ap + kt * 32;
      #pragma unroll
      for (int mt = 0; mt < 4; ++mt) {
        short8 a = *(const short8*)(apk + mt * (16 * LROW));
        acc[mt][0] = __builtin_amdgcn_mfma_f32_16x16x32_bf16(a, b0, acc[mt][0], 0, 0, 0);
        acc[mt][1] = __builtin_amdgcn_mfma_f32_16x16x32_bf16(a, b1, acc[mt][1], 0, 0, 0);
        acc[mt][2] = __builtin_amdgcn_mfma_f32_16x16x32_bf16(a, b2, acc[mt][2], 0, 0, 0);
        acc[mt][3] = __builtin_amdgcn_mfma_f32_16x16x32_bf16(a, b3, acc[mt][3], 0, 0, 0);
      }
    }
    int colb = jt * 128 + wv * 16 + m16;
    #pragma unroll
    for (int mt = 0; mt < 4; ++mt) {
      #pragma unroll
      for (int r = 0; r < 4; ++r) {
        int row = mt * 16 + quad * 4 + r;
        float cn = sigm(acc[mt][1][r]) * c_reg[jt][mt][r]
                 + sigm(acc[mt][0][r]) * tanh_f(acc[mt][2][r]);
        c_reg[jt][mt][r] = cn;
        nxt[row * LROW + colb] = (short)f2bf(sigm(acc[mt][3][r]) * tanh_f(cn));
      }
    }
  }
}

// ---------------- encoder: 128 blocks x 512 threads, 64 rows each ------------
__global__ __launch_bounds__(512, 2) void lstm_encoder(
    const float* __restrict__ speed, const float* __restrict__ pos,
    const short* __restrict__ wpack,
    short* __restrict__ h_enc, float* __restrict__ c_enc)
{
  extern __shared__ short smem[];
  short* bufA = smem;
  short* bufB = smem + BUF_SH;
  int tid = threadIdx.x;
  int b = blockIdx.x;
  int enc = (b & 7) >> 2;                     // XCDs 0-3: speed, 4-7: pos
  int gl = (b & 3) + ((b >> 3) << 2);         // 0..63
  int r0 = gl * 64;
  const float* xin = enc ? pos : speed;
  const short* wm = wpack + (size_t)enc * WMAT;

  for (int i = tid; i < 2 * BUF_SH; i += 512) smem[i] = 0;
  __syncthreads();
  if (tid < 64) {                             // bias col = 1.0 in BOTH buffers
    bufA[tid * LROW + 516] = (short)0x3F80;
    bufB[tid * LROW + 516] = (short)0x3F80;
  }
  if (tid < 256) {                            // x(0) into bufA
    int r = tid >> 2, c = tid & 3;
    bufA[r * LROW + 512 + c] = (short)f2bf(xin[(size_t)(r0 + r) * 64 + c]);
  }

  int lane = tid & 63, wv = tid >> 6;
  float c_reg[4][4][4];
  #pragma unroll
  for (int jt = 0; jt < 4; ++jt)
    #pragma unroll
    for (int mt = 0; mt < 4; ++mt)
      #pragma unroll
      for (int r = 0; r < 4; ++r) c_reg[jt][mt][r] = 0.0f;

  __syncthreads();

  for (int t = 0; t < 16; ++t) {
    const short* cur = (t & 1) ? bufB : bufA;
    short* nxt = (t & 1) ? bufA : bufB;
    lstm_step(cur, nxt, wm, lane, wv, c_reg);
    if (t < 15 && tid < 256) {                // x(t+1) into nxt
      int r = tid >> 2, c = tid & 3;
      nxt[r * LROW + 512 + c] = (short)f2bf(xin[(size_t)(r0 + r) * 64 + (t + 1) * 4 + c]);
    }
    __syncthreads();
  }

  // final h(16) is in bufA (t=15 wrote nxt=bufA); store h bf16 + c fp32
  for (int i = tid; i < 4096; i += 512) {
    int row = i >> 6, ch = i & 63;
    *(short8*)(h_enc + ((size_t)(enc * B_TOT + r0 + row) << 9) + ch * 8) =
        *(const short8*)(bufA + row * LROW + ch * 8);
  }
  int m16 = lane & 15, quad = lane >> 4;
  #pragma unroll
  for (int jt = 0; jt < 4; ++jt) {
    int colb = jt * 128 + wv * 16 + m16;
    #pragma unroll
    for (int mt = 0; mt < 4; ++mt)
      #pragma unroll
      for (int r = 0; r < 4; ++r) {
        int row = mt * 16 + quad * 4 + r;
        c_enc[((size_t)(enc * B_TOT + r0 + row) << 9) + colb] = c_reg[jt][mt][r];
      }
  }
}

// ---------------- decoder: 128 blocks x 512 threads, 64 rows each ------------
__global__ __launch_bounds__(512, 2) void lstm_decoder(
    const float* __restrict__ speed, const float* __restrict__ pos,
    const short* __restrict__ wpack,
    const short* __restrict__ h_enc, const float* __restrict__ c_enc,
    const float* __restrict__ W_fs, const float* __restrict__ b_fs,
    const float* __restrict__ W_fc, const float* __restrict__ b_fc,
    const float* __restrict__ W_emb, const float* __restrict__ b_emb,
    float* __restrict__ out)
{
  extern __shared__ short smem[];
  short* bufA = smem;
  short* bufB = smem + BUF_SH;
  int tid = threadIdx.x;
  int b = blockIdx.x;
  int chain = (b & 7) >> 2;                   // XCDs 0-3: speed chain, 4-7: crossing
  int gl = (b & 3) + ((b >> 3) << 2);
  int r0 = gl * 64;
  const short* wm = wpack + (size_t)(2 + chain) * WMAT;

  for (int i = tid; i < 2 * BUF_SH; i += 512) smem[i] = 0;
  __syncthreads();
  if (tid < 64) {
    bufA[tid * LROW + 516] = (short)0x3F80;
    bufB[tid * LROW + 516] = (short)0x3F80;
  }
  // h0 = h_se + h_pe into bufA
  for (int i = tid; i < 4096; i += 512) {
    int row = i >> 6, ch = i & 63;
    const short8 a = *(const short8*)(h_enc + ((size_t)(r0 + row) << 9) + ch * 8);
    const short8 c2 = *(const short8*)(h_enc + ((size_t)(B_TOT + r0 + row) << 9) + ch * 8);
    short8 v;
    #pragma unroll
    for (int j = 0; j < 8; ++j)
      v[j] = (short)f2bf(bf2f((unsigned short)a[j]) + bf2f((unsigned short)c2[j]));
    *(short8*)(bufA + row * LROW + ch * 8) = v;
  }
  if (tid < 256) {                            // x(0) = last observation
    const float* last = chain ? pos : speed;
    int r = tid >> 2, c = tid & 3;
    bufA[r * LROW + 512 + c] = (short)f2bf(last[(size_t)(r0 + r) * 64 + 60 + c]);
  }

  int lane = tid & 63, wv = tid >> 6;
  int m16 = lane & 15, quad = lane >> 4;
  float c_reg[4][4][4];
  #pragma unroll
  for (int jt = 0; jt < 4; ++jt) {
    int colb = jt * 128 + wv * 16 + m16;
    #pragma unroll
    for (int mt = 0; mt < 4; ++mt)
      #pragma unroll
      for (int r = 0; r < 4; ++r) {
        int row = mt * 16 + quad * 4 + r;
        size_t gi = ((size_t)(r0 + row) << 9) + colb;
        c_reg[jt][mt][r] = c_enc[gi] + c_enc[gi + (((size_t)B_TOT) << 9)];
      }
  }
  __syncthreads();

  for (int t = 0; t < 32; ++t) {
    const short* cur = (t & 1) ? bufB : bufA;
    short* nxt = (t & 1) ? bufA : bufB;
    lstm_step(cur, nxt, wm, lane, wv, c_reg);
    __syncthreads();                          // S1: h(t+1) complete in nxt

    // heads on h(t+1): wave wv owns rows [wv*8, wv*8+8)
    if (chain == 0) {
      float w0[8], w1[8], w2[8], w3[8];
      {
        float4 a, c2;
        a = *(const float4*)(W_fs + 0 * 512 + lane * 8); c2 = *(const float4*)(W_fs + 0 * 512 + lane * 8 + 4);
        w0[0]=a.x; w0[1]=a.y; w0[2]=a.z; w0[3]=a.w; w0[4]=c2.x; w0[5]=c2.y; w0[6]=c2.z; w0[7]=c2.w;
        a = *(const float4*)(W_fs + 1 * 512 + lane * 8); c2 = *(const float4*)(W_fs + 1 * 512 + lane * 8 + 4);
        w1[0]=a.x; w1[1]=a.y; w1[2]=a.z; w1[3]=a.w; w1[4]=c2.x; w1[5]=c2.y; w1[6]=c2.z; w1[7]=c2.w;
        a = *(const float4*)(W_fs + 2 * 512 + lane * 8); c2 = *(const float4*)(W_fs + 2 * 512 + lane * 8 + 4);
        w2[0]=a.x; w2[1]=a.y; w2[2]=a.z; w2[3]=a.w; w2[4]=c2.x; w2[5]=c2.y; w2[6]=c2.z; w2[7]=c2.w;
        a = *(const float4*)(W_fs + 3 * 512 + lane * 8); c2 = *(const float4*)(W_fs + 3 * 512 + lane * 8 + 4);
        w3[0]=a.x; w3[1]=a.y; w3[2]=a.z; w3[3]=a.w; w3[4]=c2.x; w3[5]=c2.y; w3[6]=c2.z; w3[7]=c2.w;
      }
      float hb0 = b_fs[0], hb1 = b_fs[1], hb2 = b_fs[2], hb3 = b_fs[3];
      #pragma unroll 1
      for (int i = 0; i < 8; ++i) {
        int row = wv * 8 + i;
        short8 hv8 = *(const short8*)(nxt + row * LROW + lane * 8);
        float p0 = 0.f, p1 = 0.f, p2 = 0.f, p3 = 0.f;
        #pragma unroll
        for (int j = 0; j < 8; ++j) {
          float hv = bf2f((unsigned short)hv8[j]);
          p0 += hv * w0[j]; p1 += hv * w1[j]; p2 += hv * w2[j]; p3 += hv * w3[j];
        }
        #pragma unroll
        for (int off = 32; off > 0; off >>= 1) {
          p0 += __shfl_xor(p0, off); p1 += __shfl_xor(p1, off);
          p2 += __shfl_xor(p2, off); p3 += __shfl_xor(p3, off);
        }
        float s0 = fminf(fmaxf(p0 + hb0, -100.0f), 100.0f);
        float s1 = fminf(fmaxf(p1 + hb1, -100.0f), 100.0f);
        float s2 = fminf(fmaxf(p2 + hb2, -100.0f), 100.0f);
        float s3 = fminf(fmaxf(p3 + hb3, -100.0f), 100.0f);
        if (lane < 4) {
          float v = (lane == 0) ? s0 : (lane == 1) ? s1 : (lane == 2) ? s2 : s3;
          out[(size_t)(r0 + row) * 128 + t * 4 + lane] = v;
          nxt[row * LROW + 512 + lane] = (short)f2bf(v);     // ls feedback
        }
      }
    } else {
      float w0[8], w1[8];
      {
        float4 a, c2;
        a = *(const float4*)(W_fc + 0 * 512 + lane * 8); c2 = *(const float4*)(W_fc + 0 * 512 + lane * 8 + 4);
        w0[0]=a.x; w0[1]=a.y; w0[2]=a.z; w0[3]=a.w; w0[4]=c2.x; w0[5]=c2.y; w0[6]=c2.z; w0[7]=c2.w;
        a = *(const float4*)(W_fc + 1 * 512 + lane * 8); c2 = *(const float4*)(W_fc + 1 * 512 + lane * 8 + 4);
        w1[0]=a.x; w1[1]=a.y; w1[2]=a.z; w1[3]=a.w; w1[4]=c2.x; w1[5]=c2.y; w1[6]=c2.z; w1[7]=c2.w;
      }
      float hb0 = b_fc[0], hb1 = b_fc[1];
      float we0 = W_emb[0], we1 = W_emb[1], we2 = W_emb[2], we3 = W_emb[3];
      float we4 = W_emb[4], we5 = W_emb[5], we6 = W_emb[6], we7 = W_emb[7];
      float be0 = b_emb[0], be1 = b_emb[1], be2 = b_emb[2], be3 = b_emb[3];
      #pragma unroll 1
      for (int i = 0; i < 8; ++i) {
        int row = wv * 8 + i;
        short8 hv8 = *(const short8*)(nxt + row * LROW + lane * 8);
        float p0 = 0.f, p1 = 0.f;
        #pragma unroll
        for (int j = 0; j < 8; ++j) {
          float hv = bf2f((unsigned short)hv8[j]);
          p0 += hv * w0[j]; p1 += hv * w1[j];
        }
        #pragma unroll
        for (int off = 32; off > 0; off >>= 1) {
          p0 += __shfl_xor(p0, off); p1 += __shfl_xor(p1, off);
        }
        float it0 = fmaxf(p0 + hb0, 0.0f);
        float it1 = fmaxf(p1 + hb1, 0.0f);
        if (lane < 4) {
          float wa = (lane == 0) ? we0 : (lane == 1) ? we2 : (lane == 2) ? we4 : we6;
          float wb = (lane == 0) ? we1 : (lane == 1) ? we3 : (lane == 2) ? we5 : we7;
          float bo = (lane == 0) ? be0 : (lane == 1) ? be1 : (lane == 2) ? be2 : be3;
          nxt[row * LROW + 512 + lane] =
              (short)f2bf(fmaxf(wa * it0 + wb * it1 + bo, 0.0f));  // lp feedback
        }
        if (t == 31 && lane < 2) {
          float m = fmaxf(it0, it1);
          float e0 = __expf(it0 - m), e1 = __expf(it1 - m);
          float v = ((lane == 0) ? e0 : e1) * rcpf(e0 + e1);
          out[(size_t)524288 + (size_t)(r0 + row) * 2 + lane] = v;
        }
      }
    }
    __syncthreads();                          // S2: feedback in nxt before t+1
  }
}

extern "C" void kernel_launch(void* const* d_in, const int* in_sizes, int n_in,
                              void* d_out, int out_size, void* d_ws, size_t ws_size,
                              hipStream_t stream)
{
  const float* speed    = (const float*)d_in[0];
  const float* pos      = (const float*)d_in[1];
  const float* enc_s_Wi = (const float*)d_in[2];
  const float* enc_s_Wh = (const float*)d_in[3];
  const float* enc_s_b  = (const float*)d_in[4];
  const float* enc_p_Wi = (const float*)d_in[5];
  const float* enc_p_Wh = (const float*)d_in[6];
  const float* enc_p_b  = (const float*)d_in[7];
  const float* dec_s_Wi = (const float*)d_in[8];
  const float* dec_s_Wh = (const float*)d_in[9];
  const float* dec_s_b  = (const float*)d_in[10];
  const float* dec_i_Wi = (const float*)d_in[11];
  const float* dec_i_Wh = (const float*)d_in[12];
  const float* dec_i_b  = (const float*)d_in[13];
  const float* W_fs     = (const float*)d_in[14];
  const float* b_fs     = (const float*)d_in[15];
  const float* W_fc     = (const float*)d_in[16];
  const float* b_fc     = (const float*)d_in[17];
  const float* W_emb    = (const float*)d_in[18];
  const float* b_emb    = (const float*)d_in[19];
  float* out = (float*)d_out;

  char* ws = (char*)d_ws;
  short* wpack = (short*)ws;                       //  8,912,896 B
  short* h_enc = (short*)(ws + 8912896);           //  8,388,608 B (2 x 4096 x 512 bf16)
  float* c_enc = (float*)(ws + 17301504);          // 16,777,216 B (2 x 4096 x 512 f32)

  const int dynLDS = 2 * BUF_SH * 2;               // 141,312 B
  hipFuncSetAttribute((const void*)lstm_encoder,
                      hipFuncAttributeMaxDynamicSharedMemorySize, dynLDS);
  hipFuncSetAttribute((const void*)lstm_decoder,
                      hipFuncAttributeMaxDynamicSharedMemorySize, dynLDS);

  prep_weights<<<17408, 256, 0, stream>>>(
      enc_s_Wh, enc_s_Wi, enc_s_b,
      enc_p_Wh, enc_p_Wi, enc_p_b,
      dec_s_Wh, dec_s_Wi, dec_s_b,
      dec_i_Wh, dec_i_Wi, dec_i_b,
      wpack);
  lstm_encoder<<<128, 512, dynLDS, stream>>>(speed, pos, wpack, h_enc, c_enc);
  lstm_decoder<<<128, 512, dynLDS, stream>>>(speed, pos, wpack, h_enc, c_enc,
                                             W_fs, b_fs, W_fc, b_fc, W_emb, b_emb, out);
}